// Round 2
// baseline (134.086 us; speedup 1.0000x reference)
//
#include <hip/hip_runtime.h>

// HungarianMatcher cost matrix: C[n,t] = 5*L1(box_n,box_t) + 2*(pos-neg)[n,id_t] - 2*GIoU(n,t)
// bs=16, nq=900 -> N=14400 rows; T=1600 targets; nc=91 classes.
// Block = 8 rows x 400 float4-columns, 448 threads (7 waves).
// R2 theory: kernel is stall-bound at ~44% occupancy (2 blocks/CU, VGPR-capped).
// Changes vs R1 (121.3 us):
//  - VGPR diet: pboxes read per-row via block-uniform address (s_load -> SGPR,
//    no VGPR array); only target CORNERS kept in registers (16 VGPR); tw/th/
//    area/centers recomputed per element (+5 VALU/elem, cheap vs occupancy).
//  - __launch_bounds__(448, 7): cap VGPR at 73 -> 4 blocks/CU (28 waves),
//    doubling wave parallelism to hide block-prologue + memory latency.
//  - plain stores kept (R0 vs R1 proved NT-vs-plain is neutral).

#define NC 91
#define TT 1600
#define T4 (TT / 4)        // 400 float4 columns
#define ROWS 8
#define NTHREADS 448

typedef float vfloat4 __attribute__((ext_vector_type(4)));

__global__ __launch_bounds__(NTHREADS, 7) void matcher_kernel(
    const float* __restrict__ logits,      // [N, 91]
    const float4* __restrict__ pboxes,     // [N] (cx,cy,w,h)
    const int4* __restrict__ tids,         // [T/4]
    const float4* __restrict__ tboxes,     // [T] (cx,cy,w,h)
    vfloat4* __restrict__ out)             // [N, T/4]
{
    __shared__ float tab[ROWS][NC];        // 2*(pos-neg) + 2 per (row, class)

    const int n0 = blockIdx.x * ROWS;
    const int tid = threadIdx.x;
    const bool active = (tid < T4);

    // --- issue t-side vector loads FIRST; latency hides under tab build ---
    int4 ids = {0, 0, 0, 0};
    float4 tb[4];
    if (active) {
        ids = tids[tid];
#pragma unroll
        for (int j = 0; j < 4; ++j) tb[j] = tboxes[tid * 4 + j];
    }

    // --- per-block precompute: focal class-cost table (scaled/shifted) ---
    for (int i = tid; i < ROWS * NC; i += NTHREADS) {
        const int r = i / NC, c = i - r * NC;
        const float x = logits[(size_t)(n0 + r) * NC + c];
        const float p = __builtin_amdgcn_rcpf(1.f + __expf(-x));  // sigmoid
        const float omp = 1.f - p;
        const float neg = 0.75f * p * p * (-__logf(omp + 1e-8f));
        const float pos = 0.25f * omp * omp * (-__logf(p + 1e-8f));
        tab[r][c] = 2.f * (pos - neg) + 2.f;   // fold COST_CLASS and giou's "+1"
    }
    __syncthreads();

    if (!active) return;

    const int idv[4] = {ids.x, ids.y, ids.z, ids.w};
    // keep ONLY corners in VGPRs (16 regs of target state)
    float tx0[4], ty0[4], tx1[4], ty1[4];
#pragma unroll
    for (int j = 0; j < 4; ++j) {
        tx0[j] = tb[j].x - 0.5f * tb[j].z;
        ty0[j] = tb[j].y - 0.5f * tb[j].w;
        tx1[j] = tb[j].x + 0.5f * tb[j].z;
        ty1[j] = tb[j].y + 0.5f * tb[j].w;
    }

#pragma unroll
    for (int r = 0; r < ROWS; ++r) {
        // block-uniform address -> scalar load, lives in SGPRs (no VGPR cost)
        const float4 b = pboxes[n0 + r];
        const float pcx = b.x, pcy = b.y, pw = b.z, ph = b.w;
        const float px0 = pcx - 0.5f * pw, py0 = pcy - 0.5f * ph;
        const float px1 = pcx + 0.5f * pw, py1 = pcy + 0.5f * ph;
        const float pa  = pw * ph;
        vfloat4 res;
#pragma unroll
        for (int j = 0; j < 4; ++j) {
            // recompute target derived values (saves 20 VGPRs vs caching)
            const float tw = tx1[j] - tx0[j];
            const float th = ty1[j] - ty0[j];
            // intersection (raw, may be negative)
            const float iwr = fminf(px1, tx1[j]) - fmaxf(px0, tx0[j]);
            const float ihr = fminf(py1, ty1[j]) - fmaxf(py0, ty0[j]);
            const float inter = fmaxf(iwr, 0.f) * fmaxf(ihr, 0.f);
            const float uni = pa + tw * th - inter;
            // enclosing box via min+max identity (clamp is a no-op: w,h>=0)
            const float ew = (pw + tw) - iwr;
            const float eh = (ph + th) - ihr;
            const float ae = ew * eh;
            const float tcx = tx0[j] + 0.5f * tw;
            const float tcy = ty0[j] + 0.5f * th;
            const float l1 = fabsf(pcx - tcx) + fabsf(pcy - tcy)
                           + fabsf(pw - tw) + fabsf(ph - th);
            // res = 5*L1 + [2*(pos-neg)+2] - 2*inter/uni - 2*uni/ae
            res[j] = 5.f * l1 + tab[r][idv[j]]
                   - 2.f * inter * __builtin_amdgcn_rcpf(uni)
                   - 2.f * uni * __builtin_amdgcn_rcpf(ae);
        }
        out[(size_t)(n0 + r) * T4 + tid] = res;   // plain store: L2/L3 absorbs
    }
}

extern "C" void kernel_launch(void* const* d_in, const int* in_sizes, int n_in,
                              void* d_out, int out_size, void* d_ws, size_t ws_size,
                              hipStream_t stream) {
    const float* logits  = (const float*)d_in[0];
    const float4* pboxes = (const float4*)d_in[1];
    const int4* tids     = (const int4*)d_in[2];
    const float4* tboxes = (const float4*)d_in[3];
    vfloat4* out = (vfloat4*)d_out;
    const int N = in_sizes[1] / 4;  // 14400 rows
    matcher_kernel<<<N / ROWS, NTHREADS, 0, stream>>>(logits, pboxes, tids, tboxes, out);
}

// Round 4
// 121.744 us; speedup vs baseline: 1.1014x; 1.1014x over previous
//
#include <hip/hip_runtime.h>

// HungarianMatcher cost matrix: C[n,t] = 5*L1(box_n,box_t) + 2*(pos-neg)[n,id_t] - 2*GIoU(n,t)
// bs=16, nq=900 -> N=14400 rows; T=1600 targets; nc=91 classes.
// Block = 8 rows x 400 float4-columns, 448 threads (7 waves).
// R4 == R3 resubmitted verbatim (R3 bench was an infra failure: "container
// failed twice" — no timing/counters; single-variable chain preserved).
// R3: single-variable change vs R2 (134.1 us, regressed from R1's 121.3):
//  - __launch_bounds__(448, 6) instead of (448, 7). The 7-wave/EU cap forced
//    VGPR<=73 and the allocator spilled (scratch traffic visible as FETCH_SIZE
//    bump in R2's profile). 6 waves/EU caps at 85 VGPRs -> diet code fits
//    without spills -> 3 blocks/CU (21 waves, 5.25/SIMD) vs R1's 2 blocks
//    (14 waves). +50% TLP to hide LDS-gather latency and prologue barriers.
//  - everything else identical to R2: corner-only target state (16 VGPR),
//    per-row block-uniform pbox s_loads, plain stores.

#define NC 91
#define TT 1600
#define T4 (TT / 4)        // 400 float4 columns
#define ROWS 8
#define NTHREADS 448

typedef float vfloat4 __attribute__((ext_vector_type(4)));

__global__ __launch_bounds__(NTHREADS, 6) void matcher_kernel(
    const float* __restrict__ logits,      // [N, 91]
    const float4* __restrict__ pboxes,     // [N] (cx,cy,w,h)
    const int4* __restrict__ tids,         // [T/4]
    const float4* __restrict__ tboxes,     // [T] (cx,cy,w,h)
    vfloat4* __restrict__ out)             // [N, T/4]
{
    __shared__ float tab[ROWS][NC];        // 2*(pos-neg) + 2 per (row, class)

    const int n0 = blockIdx.x * ROWS;
    const int tid = threadIdx.x;
    const bool active = (tid < T4);

    // --- issue t-side vector loads FIRST; latency hides under tab build ---
    int4 ids = {0, 0, 0, 0};
    float4 tb[4];
    if (active) {
        ids = tids[tid];
#pragma unroll
        for (int j = 0; j < 4; ++j) tb[j] = tboxes[tid * 4 + j];
    }

    // --- per-block precompute: focal class-cost table (scaled/shifted) ---
    for (int i = tid; i < ROWS * NC; i += NTHREADS) {
        const int r = i / NC, c = i - r * NC;
        const float x = logits[(size_t)(n0 + r) * NC + c];
        const float p = __builtin_amdgcn_rcpf(1.f + __expf(-x));  // sigmoid
        const float omp = 1.f - p;
        const float neg = 0.75f * p * p * (-__logf(omp + 1e-8f));
        const float pos = 0.25f * omp * omp * (-__logf(p + 1e-8f));
        tab[r][c] = 2.f * (pos - neg) + 2.f;   // fold COST_CLASS and giou's "+1"
    }
    __syncthreads();

    if (!active) return;

    const int idv[4] = {ids.x, ids.y, ids.z, ids.w};
    // keep ONLY corners in VGPRs (16 regs of target state)
    float tx0[4], ty0[4], tx1[4], ty1[4];
#pragma unroll
    for (int j = 0; j < 4; ++j) {
        tx0[j] = tb[j].x - 0.5f * tb[j].z;
        ty0[j] = tb[j].y - 0.5f * tb[j].w;
        tx1[j] = tb[j].x + 0.5f * tb[j].z;
        ty1[j] = tb[j].y + 0.5f * tb[j].w;
    }

#pragma unroll
    for (int r = 0; r < ROWS; ++r) {
        // block-uniform address -> scalar load, lives in SGPRs (no VGPR cost)
        const float4 b = pboxes[n0 + r];
        const float pcx = b.x, pcy = b.y, pw = b.z, ph = b.w;
        const float px0 = pcx - 0.5f * pw, py0 = pcy - 0.5f * ph;
        const float px1 = pcx + 0.5f * pw, py1 = pcy + 0.5f * ph;
        const float pa  = pw * ph;
        vfloat4 res;
#pragma unroll
        for (int j = 0; j < 4; ++j) {
            // recompute target derived values (saves 20 VGPRs vs caching)
            const float tw = tx1[j] - tx0[j];
            const float th = ty1[j] - ty0[j];
            // intersection (raw, may be negative)
            const float iwr = fminf(px1, tx1[j]) - fmaxf(px0, tx0[j]);
            const float ihr = fminf(py1, ty1[j]) - fmaxf(py0, ty0[j]);
            const float inter = fmaxf(iwr, 0.f) * fmaxf(ihr, 0.f);
            const float uni = pa + tw * th - inter;
            // enclosing box via min+max identity (clamp is a no-op: w,h>=0)
            const float ew = (pw + tw) - iwr;
            const float eh = (ph + th) - ihr;
            const float ae = ew * eh;
            const float tcx = tx0[j] + 0.5f * tw;
            const float tcy = ty0[j] + 0.5f * th;
            const float l1 = fabsf(pcx - tcx) + fabsf(pcy - tcy)
                           + fabsf(pw - tw) + fabsf(ph - th);
            // res = 5*L1 + [2*(pos-neg)+2] - 2*inter/uni - 2*uni/ae
            res[j] = 5.f * l1 + tab[r][idv[j]]
                   - 2.f * inter * __builtin_amdgcn_rcpf(uni)
                   - 2.f * uni * __builtin_amdgcn_rcpf(ae);
        }
        out[(size_t)(n0 + r) * T4 + tid] = res;   // plain store: L2/L3 absorbs
    }
}

extern "C" void kernel_launch(void* const* d_in, const int* in_sizes, int n_in,
                              void* d_out, int out_size, void* d_ws, size_t ws_size,
                              hipStream_t stream) {
    const float* logits  = (const float*)d_in[0];
    const float4* pboxes = (const float4*)d_in[1];
    const int4* tids     = (const int4*)d_in[2];
    const float4* tboxes = (const float4*)d_in[3];
    vfloat4* out = (vfloat4*)d_out;
    const int N = in_sizes[1] / 4;  // 14400 rows
    matcher_kernel<<<N / ROWS, NTHREADS, 0, stream>>>(logits, pboxes, tids, tboxes, out);
}

// Round 5
// 121.582 us; speedup vs baseline: 1.1028x; 1.0013x over previous
//
#include <hip/hip_runtime.h>

// HungarianMatcher cost matrix: C[n,t] = 5*L1(box_n,box_t) + 2*(pos-neg)[n,id_t] - 2*GIoU(n,t)
// bs=16, nq=900 -> N=14400 rows; T=1600 targets; nc=91 classes.
// R5: ROWS 8 -> 16 (900 blocks), testing the per-block-overhead/convoy theory.
// Evidence so far: NT-vs-plain stores neutral (R0/R1), VALU count -20% neutral
// (R1/R4), VGPR cap 85 neutral (R4), spills +13us (R2). Matcher ~55us vs
// ~17-20us floor -> stall-bound on something structural; prologue amortization
// is the last untested lever.
//  - 16 rows/block: halves block count, barriers, and t-data (tids/tboxes)
//    re-reads per block.
//  - prologue rewritten: focal transform is ELEMENTWISE on the logit, and a
//    16-row logits slice is a contiguous 16B-aligned run of 1456 floats ->
//    float4 global loads + float4 LDS stores, flat tab[], no int division.
//  - main-loop gather: tab[r*91 + id] -> ds_read base id*4 + const offset.
//  - __launch_bounds__(448, 4): proven-safe 128-VGPR cap (no spill risk on the
//    16x-unrolled loop; 3-blocks/CU axis already shown neutral in R4).

#define NC 91
#define TT 1600
#define T4 (TT / 4)         // 400 float4 columns
#define ROWS 16
#define NTHREADS 448
#define TABN (ROWS * NC)    // 1456 floats
#define TAB4 (TABN / 4)     // 364 float4

typedef float vfloat4 __attribute__((ext_vector_type(4)));

__device__ __forceinline__ float focal_tab(float x) {
    const float p = __builtin_amdgcn_rcpf(1.f + __expf(-x));  // sigmoid
    const float omp = 1.f - p;
    const float neg = 0.75f * p * p * (-__logf(omp + 1e-8f));
    const float pos = 0.25f * omp * omp * (-__logf(p + 1e-8f));
    return 2.f * (pos - neg) + 2.f;   // fold COST_CLASS and giou's "+1"
}

__global__ __launch_bounds__(NTHREADS, 4) void matcher_kernel(
    const float* __restrict__ logits,      // [N, 91]
    const float4* __restrict__ pboxes,     // [N] (cx,cy,w,h)
    const int4* __restrict__ tids,         // [T/4]
    const float4* __restrict__ tboxes,     // [T] (cx,cy,w,h)
    vfloat4* __restrict__ out)             // [N, T/4]
{
    __shared__ float tab[TABN];            // flat [ROWS][NC]

    const int n0 = blockIdx.x * ROWS;
    const int tid = threadIdx.x;
    const bool active = (tid < T4);

    // --- issue t-side vector loads FIRST; latency hides under tab build ---
    int4 ids = {0, 0, 0, 0};
    float4 tb[4];
    if (active) {
        ids = tids[tid];
#pragma unroll
        for (int j = 0; j < 4; ++j) tb[j] = tboxes[tid * 4 + j];
    }

    // --- prologue: coalesced float4 logits -> elementwise focal -> LDS ---
    if (tid < TAB4) {
        const float4 v = *reinterpret_cast<const float4*>(
            logits + (size_t)n0 * NC + 4 * (size_t)tid);
        float4 o;
        o.x = focal_tab(v.x);
        o.y = focal_tab(v.y);
        o.z = focal_tab(v.z);
        o.w = focal_tab(v.w);
        *reinterpret_cast<float4*>(&tab[4 * tid]) = o;
    }
    __syncthreads();

    if (!active) return;

    const int idv[4] = {ids.x, ids.y, ids.z, ids.w};
    // keep ONLY corners in VGPRs (16 regs of target state)
    float tx0[4], ty0[4], tx1[4], ty1[4];
#pragma unroll
    for (int j = 0; j < 4; ++j) {
        tx0[j] = tb[j].x - 0.5f * tb[j].z;
        ty0[j] = tb[j].y - 0.5f * tb[j].w;
        tx1[j] = tb[j].x + 0.5f * tb[j].z;
        ty1[j] = tb[j].y + 0.5f * tb[j].w;
    }

#pragma unroll
    for (int r = 0; r < ROWS; ++r) {
        // block-uniform address -> scalar load, lives in SGPRs (no VGPR cost)
        const float4 b = pboxes[n0 + r];
        const float pcx = b.x, pcy = b.y, pw = b.z, ph = b.w;
        const float px0 = pcx - 0.5f * pw, py0 = pcy - 0.5f * ph;
        const float px1 = pcx + 0.5f * pw, py1 = pcy + 0.5f * ph;
        const float pa  = pw * ph;
        vfloat4 res;
#pragma unroll
        for (int j = 0; j < 4; ++j) {
            // recompute target derived values (saves 20 VGPRs vs caching)
            const float tw = tx1[j] - tx0[j];
            const float th = ty1[j] - ty0[j];
            // intersection (raw, may be negative)
            const float iwr = fminf(px1, tx1[j]) - fmaxf(px0, tx0[j]);
            const float ihr = fminf(py1, ty1[j]) - fmaxf(py0, ty0[j]);
            const float inter = fmaxf(iwr, 0.f) * fmaxf(ihr, 0.f);
            const float uni = pa + tw * th - inter;
            // enclosing box via min+max identity (clamp is a no-op: w,h>=0)
            const float ew = (pw + tw) - iwr;
            const float eh = (ph + th) - ihr;
            const float ae = ew * eh;
            const float tcx = tx0[j] + 0.5f * tw;
            const float tcy = ty0[j] + 0.5f * th;
            const float l1 = fabsf(pcx - tcx) + fabsf(pcy - tcy)
                           + fabsf(pw - tw) + fabsf(ph - th);
            // res = 5*L1 + [2*(pos-neg)+2] - 2*inter/uni - 2*uni/ae
            res[j] = 5.f * l1 + tab[r * NC + idv[j]]
                   - 2.f * inter * __builtin_amdgcn_rcpf(uni)
                   - 2.f * uni * __builtin_amdgcn_rcpf(ae);
        }
        out[(size_t)(n0 + r) * T4 + tid] = res;   // plain store: L2/L3 absorbs
    }
}

extern "C" void kernel_launch(void* const* d_in, const int* in_sizes, int n_in,
                              void* d_out, int out_size, void* d_ws, size_t ws_size,
                              hipStream_t stream) {
    const float* logits  = (const float*)d_in[0];
    const float4* pboxes = (const float4*)d_in[1];
    const int4* tids     = (const int4*)d_in[2];
    const float4* tboxes = (const float4*)d_in[3];
    vfloat4* out = (vfloat4*)d_out;
    const int N = in_sizes[1] / 4;  // 14400 rows
    matcher_kernel<<<N / ROWS, NTHREADS, 0, stream>>>(logits, pboxes, tids, tboxes, out);
}